// Round 1
// baseline (500.367 us; speedup 1.0000x reference)
//
#include <hip/hip_runtime.h>
#include <math.h>

#define DM 256
#define LSEQ 2048
#define BATCH 8
#define NLAYER 8
#define EMAX 192
#define LN_EPS 1e-5f
#define KC 32
#define MR 32

// ---------------- init: h[b,t,c] = x[b,t,0]*inW[c] + inb[c] ----------------
__global__ void k_init(const float* __restrict__ x, const float* __restrict__ inW,
                       const float* __restrict__ inb, float* __restrict__ h) {
    int i4 = blockIdx.x * blockDim.x + threadIdx.x;   // float4 index
    int e = i4 * 4;
    int row = e >> 8;          // b*L + t
    int c = e & 255;
    float xv = x[row];
    float4 w  = *(const float4*)&inW[c];
    float4 bb = *(const float4*)&inb[c];
    float4 o;
    o.x = xv * w.x + bb.x;
    o.y = xv * w.y + bb.y;
    o.z = xv * w.z + bb.z;
    o.w = xv * w.w + bb.w;
    *(float4*)&h[e] = o;
}

// ---------------- zero pooled accumulator ----------------
__global__ void k_zero(float* __restrict__ p) {
    int i = blockIdx.x * blockDim.x + threadIdx.x;
    float4 z = {0.f, 0.f, 0.f, 0.f};
    *(float4*)&p[i * 4] = z;
}

// ---------------- per-layer prep: P[b,c], logA[c], CB[c] ----------------
__global__ void k_prep(const float* __restrict__ h, const float* __restrict__ Ap,
                       const float* __restrict__ Bp, const float* __restrict__ Cp,
                       float* __restrict__ P, float* __restrict__ logA,
                       float* __restrict__ CB) {
    __shared__ float red[4][DM];
    int b = blockIdx.x;
    int tid = threadIdx.x;
    int cq = (tid & 63) * 4;       // c0 (group of 4 channels)
    int j  = tid >> 6;             // s-chunk 0..3
    float4 ap = *(const float4*)&Ap[cq];
    float4 A;
    A.x = 1.f / (1.f + expf(-ap.x));
    A.y = 1.f / (1.f + expf(-ap.y));
    A.z = 1.f / (1.f + expf(-ap.z));
    A.w = 1.f / (1.f + expf(-ap.w));
    float4 lA;
    lA.x = logf(A.x); lA.y = logf(A.y); lA.z = logf(A.z); lA.w = logf(A.w);
    int s0 = j * 49;
    int s1 = min(EMAX + 1, s0 + 49);
    float4 pw;
    pw.x = expf((float)s0 * lA.x);
    pw.y = expf((float)s0 * lA.y);
    pw.z = expf((float)s0 * lA.z);
    pw.w = expf((float)s0 * lA.w);
    float4 acc = {0.f, 0.f, 0.f, 0.f};
    for (int s = s0; s < s1; ++s) {
        float4 hv = *(const float4*)&h[(b * LSEQ + s) * DM + cq];
        acc.x += hv.x * pw.x; acc.y += hv.y * pw.y;
        acc.z += hv.z * pw.z; acc.w += hv.w * pw.w;
        pw.x *= A.x; pw.y *= A.y; pw.z *= A.z; pw.w *= A.w;
    }
    *(float4*)&red[j][cq] = acc;
    __syncthreads();
    if (j == 0) {
        float4 r0 = *(const float4*)&red[0][cq];
        float4 r1 = *(const float4*)&red[1][cq];
        float4 r2 = *(const float4*)&red[2][cq];
        float4 r3 = *(const float4*)&red[3][cq];
        float4 s;
        s.x = r0.x + r1.x + r2.x + r3.x;
        s.y = r0.y + r1.y + r2.y + r3.y;
        s.z = r0.z + r1.z + r2.z + r3.z;
        s.w = r0.w + r1.w + r2.w + r3.w;
        *(float4*)&P[b * DM + cq] = s;
    }
    if (b == 0 && j == 1) {
        *(float4*)&logA[cq] = lA;
        float4 bp = *(const float4*)&Bp[cq];
        float4 cp = *(const float4*)&Cp[cq];
        float4 cb;
        cb.x = bp.x * cp.x; cb.y = bp.y * cp.y;
        cb.z = bp.z * cp.z; cb.w = bp.w * cp.w;
        *(float4*)&CB[cq] = cb;
    }
}

__device__ __forceinline__ float gelu_exact(float v) {
    return 0.5f * v * (1.f + erff(v * 0.70710678118654752f));
}

// ---------------- fused: g=gelu(D*h+conv-tail); out2=g@pW^T+pb; y=h+out2; LN; pool ----------------
__global__ __launch_bounds__(256) void k_gemm(
    const float* __restrict__ h, float* __restrict__ hout,
    const float* __restrict__ pW, const float* __restrict__ pb,
    const float* __restrict__ lng, const float* __restrict__ lnb,
    const float* __restrict__ Dp,
    const float* __restrict__ P, const float* __restrict__ logA,
    const float* __restrict__ CB,
    float* __restrict__ pooled, int exitSlot) {
    __shared__ float gs[KC][36];       // gs[k][row]
    __shared__ float pWs[KC][260];     // pWs[k][col]
    int tid = threadIdx.x;
    int brow = blockIdx.x * MR;
    int b = brow >> 11;
    // staging mapping
    int srow = tid >> 3;               // 0..31
    int sk4  = (tid & 7) << 2;         // 0,4,...,28
    int gr = brow + srow;
    int t = gr & (LSEQ - 1);
    int u = (LSEQ - 1) - t;
    // compute mapping
    int tx = tid & 63, ty = tid >> 6;
    float acc[8][4];
#pragma unroll
    for (int i = 0; i < 8; ++i)
#pragma unroll
        for (int j = 0; j < 4; ++j) acc[i][j] = 0.f;

    for (int kc = 0; kc < DM; kc += KC) {
        // ---- stage A-tile (gelu fused) ----
        {
            int c0 = kc + sk4;
            float4 hv = *(const float4*)&h[gr * DM + c0];
            float4 Dv = *(const float4*)&Dp[c0];
            float v0 = Dv.x * hv.x, v1 = Dv.y * hv.y, v2 = Dv.z * hv.z, v3 = Dv.w * hv.w;
            if (u <= EMAX) {
                float4 la = *(const float4*)&logA[c0];
                float4 cb = *(const float4*)&CB[c0];
                float4 Pv = *(const float4*)&P[b * DM + c0];
                float uf = (float)u;
                v0 += cb.x * expf(uf * la.x) * Pv.x;
                v1 += cb.y * expf(uf * la.y) * Pv.y;
                v2 += cb.z * expf(uf * la.z) * Pv.z;
                v3 += cb.w * expf(uf * la.w) * Pv.w;
            }
            gs[sk4 + 0][srow] = gelu_exact(v0);
            gs[sk4 + 1][srow] = gelu_exact(v1);
            gs[sk4 + 2][srow] = gelu_exact(v2);
            gs[sk4 + 3][srow] = gelu_exact(v3);
        }
        // ---- stage B-tile (pW transposed into LDS) ----
        {
            int k = tid & 31;
            int cbase = tid >> 5;      // 0..7
#pragma unroll
            for (int j2 = 0; j2 < 32; ++j2) {
                int c = j2 * 8 + cbase;
                pWs[k][c] = pW[c * DM + kc + k];
            }
        }
        __syncthreads();
#pragma unroll
        for (int k = 0; k < KC; ++k) {
            float4 a0 = *(const float4*)&gs[k][ty * 8];
            float4 a1 = *(const float4*)&gs[k][ty * 8 + 4];
            float4 bv = *(const float4*)&pWs[k][tx * 4];
            acc[0][0] += a0.x * bv.x; acc[0][1] += a0.x * bv.y; acc[0][2] += a0.x * bv.z; acc[0][3] += a0.x * bv.w;
            acc[1][0] += a0.y * bv.x; acc[1][1] += a0.y * bv.y; acc[1][2] += a0.y * bv.z; acc[1][3] += a0.y * bv.w;
            acc[2][0] += a0.z * bv.x; acc[2][1] += a0.z * bv.y; acc[2][2] += a0.z * bv.z; acc[2][3] += a0.z * bv.w;
            acc[3][0] += a0.w * bv.x; acc[3][1] += a0.w * bv.y; acc[3][2] += a0.w * bv.z; acc[3][3] += a0.w * bv.w;
            acc[4][0] += a1.x * bv.x; acc[4][1] += a1.x * bv.y; acc[4][2] += a1.x * bv.z; acc[4][3] += a1.x * bv.w;
            acc[5][0] += a1.y * bv.x; acc[5][1] += a1.y * bv.y; acc[5][2] += a1.y * bv.z; acc[5][3] += a1.y * bv.w;
            acc[6][0] += a1.z * bv.x; acc[6][1] += a1.z * bv.y; acc[6][2] += a1.z * bv.z; acc[6][3] += a1.z * bv.w;
            acc[7][0] += a1.w * bv.x; acc[7][1] += a1.w * bv.y; acc[7][2] += a1.w * bv.z; acc[7][3] += a1.w * bv.w;
        }
        __syncthreads();
    }
    // ---- epilogue: residual + LN + store + pooling ----
    int c0 = tx * 4;
    float4 pbv = *(const float4*)&pb[c0];
    float4 lg  = *(const float4*)&lng[c0];
    float4 lb  = *(const float4*)&lnb[c0];
    float csum0 = 0.f, csum1 = 0.f, csum2 = 0.f, csum3 = 0.f;
#pragma unroll
    for (int i = 0; i < 8; ++i) {
        int r = brow + ty * 8 + i;
        float4 hv = *(const float4*)&h[r * DM + c0];
        float y0 = hv.x + acc[i][0] + pbv.x;
        float y1 = hv.y + acc[i][1] + pbv.y;
        float y2 = hv.z + acc[i][2] + pbv.z;
        float y3 = hv.w + acc[i][3] + pbv.w;
        float s  = y0 + y1 + y2 + y3;
        float ss = y0 * y0 + y1 * y1 + y2 * y2 + y3 * y3;
#pragma unroll
        for (int off = 1; off < 64; off <<= 1) {
            s  += __shfl_xor(s, off);
            ss += __shfl_xor(ss, off);
        }
        float mean = s * (1.f / 256.f);
        float var  = ss * (1.f / 256.f) - mean * mean;
        float rstd = rsqrtf(var + LN_EPS);
        float o0 = (y0 - mean) * rstd * lg.x + lb.x;
        float o1 = (y1 - mean) * rstd * lg.y + lb.y;
        float o2 = (y2 - mean) * rstd * lg.z + lb.z;
        float o3 = (y3 - mean) * rstd * lg.w + lb.w;
        float4 ov = {o0, o1, o2, o3};
        *(float4*)&hout[r * DM + c0] = ov;
        csum0 += o0; csum1 += o1; csum2 += o2; csum3 += o3;
    }
    if (exitSlot >= 0) {
        __syncthreads();
        float* S = &pWs[0][0];          // reuse LDS: [4][256]
        S[ty * DM + c0 + 0] = csum0;
        S[ty * DM + c0 + 1] = csum1;
        S[ty * DM + c0 + 2] = csum2;
        S[ty * DM + c0 + 3] = csum3;
        __syncthreads();
        if (tid < 64) {
            int cc = tid * 4;
#pragma unroll
            for (int q = 0; q < 4; ++q) {
                float sm = S[cc + q] + S[DM + cc + q] + S[2 * DM + cc + q] + S[3 * DM + cc + q];
                atomicAdd(&pooled[exitSlot * (BATCH * DM) + b * DM + cc + q], sm);
            }
        }
    }
}

// ---------------- head: logits[e,b,n] ----------------
__global__ void k_head(const float* __restrict__ pooled, const float* __restrict__ hW,
                       const float* __restrict__ hb, float* __restrict__ out) {
    int tid = threadIdx.x;
    if (tid >= 96) return;
    int e = tid / 24;
    int r = tid % 24;
    int b = r / 3;
    int n = r % 3;
    const float* pv = &pooled[e * (BATCH * DM) + b * DM];
    const float* wv = &hW[(e * 3 + n) * DM];
    float acc = 0.f;
    for (int c = 0; c < DM; ++c) acc += pv[c] * wv[c];
    out[e * 24 + b * 3 + n] = acc * (1.f / (float)LSEQ) + hb[e * 3 + n];
}

extern "C" void kernel_launch(void* const* d_in, const int* in_sizes, int n_in,
                              void* d_out, int out_size, void* d_ws, size_t ws_size,
                              hipStream_t stream) {
    const float* x   = (const float*)d_in[0];
    const float* inW = (const float*)d_in[1];
    const float* inb = (const float*)d_in[2];
    const float* Ap  = (const float*)d_in[3];
    const float* Bp  = (const float*)d_in[4];
    const float* Cp  = (const float*)d_in[5];
    const float* Dp  = (const float*)d_in[6];
    const float* pW  = (const float*)d_in[7];
    const float* pb  = (const float*)d_in[8];
    const float* lng = (const float*)d_in[9];
    const float* lnb = (const float*)d_in[10];
    const float* hW  = (const float*)d_in[11];
    const float* hb  = (const float*)d_in[12];
    float* out = (float*)d_out;

    float* ws = (float*)d_ws;
    float* h      = ws;                         // 8*2048*256 = 4194304 floats
    float* P      = h + BATCH * LSEQ * DM;      // 2048
    float* logA   = P + BATCH * DM;             // 256
    float* CB     = logA + DM;                  // 256
    float* pooled = CB + DM;                    // 4*8*256 = 8192

    k_init<<<4096, 256, 0, stream>>>(x, inW, inb, h);
    k_zero<<<8, 256, 0, stream>>>(pooled);
    for (int l = 0; l < NLAYER; ++l) {
        k_prep<<<BATCH, 256, 0, stream>>>(h, Ap + l * DM, Bp + l * DM, Cp + l * DM,
                                          P, logA, CB);
        int ex = (l == 1) ? 0 : (l == 3) ? 1 : (l == 5) ? 2 : (l == 7) ? 3 : -1;
        k_gemm<<<(BATCH * LSEQ) / MR, 256, 0, stream>>>(
            h, h, pW + l * DM * DM, pb + l * DM, lng + l * DM, lnb + l * DM,
            Dp + l * DM, P, logA, CB, pooled, ex);
    }
    k_head<<<1, 128, 0, stream>>>(pooled, hW, hb, out);
}

// Round 2
// 323.902 us; speedup vs baseline: 1.5448x; 1.5448x over previous
//
#include <hip/hip_runtime.h>
#include <math.h>

#define DM 256
#define LSEQ 2048
#define BATCH 8
#define NLAYER 8
#define EMAX 192
#define LN_EPS 1e-5f
#define KC 32
#define APAD 40      // padded row length (u16) for 32-k chunk
#define YPAD 260     // padded row length (f32) for epilogue tile

typedef float f32x4 __attribute__((ext_vector_type(4)));
typedef short bf16x8 __attribute__((ext_vector_type(8)));
typedef unsigned short u16;
typedef unsigned short u16x4 __attribute__((ext_vector_type(4)));

__device__ __forceinline__ float gelu_exact(float v) {
    return 0.5f * v * (1.f + erff(v * 0.70710678118654752f));
}

// split fp32 -> bf16 hi (truncated, exact-subtractable) + bf16 lo (RNE of remainder)
__device__ __forceinline__ void split2(float g, u16& hi, u16& lo) {
    unsigned u = __float_as_uint(g);
    hi = (u16)(u >> 16);
    float fh = __uint_as_float(u & 0xFFFF0000u);
    float r = g - fh;
    unsigned v = __float_as_uint(r);
    v = v + 0x7FFFu + ((v >> 16) & 1u);
    lo = (u16)(v >> 16);
}

// ---------------- init: h[b,t,c] = x[b,t,0]*inW[c] + inb[c] ----------------
__global__ void k_init(const float* __restrict__ x, const float* __restrict__ inW,
                       const float* __restrict__ inb, float* __restrict__ h) {
    int i4 = blockIdx.x * blockDim.x + threadIdx.x;
    int e = i4 * 4;
    int row = e >> 8;
    int c = e & 255;
    float xv = x[row];
    float4 w  = *(const float4*)&inW[c];
    float4 bb = *(const float4*)&inb[c];
    float4 o;
    o.x = xv * w.x + bb.x;
    o.y = xv * w.y + bb.y;
    o.z = xv * w.z + bb.z;
    o.w = xv * w.w + bb.w;
    *(float4*)&h[e] = o;
}

// ---------------- prep0: logA/CB all layers, P[0], zero P[1..7] + pooled ----------------
__global__ void k_prep0(const float* __restrict__ x, const float* __restrict__ inW,
                        const float* __restrict__ inb, const float* __restrict__ Ap,
                        const float* __restrict__ Bp, const float* __restrict__ Cp,
                        float* __restrict__ P_all, float* __restrict__ logA_all,
                        float* __restrict__ CB_all, float* __restrict__ pooled) {
    int b = blockIdx.x;
    int c = threadIdx.x;
    float A0 = 1.f / (1.f + expf(-Ap[c]));
    float iw = inW[c], ib = inb[c];
    const float* xb = x + b * LSEQ;
    float pw = 1.f, acc = 0.f;
    for (int t = 0; t <= EMAX; ++t) {
        acc += (xb[t] * iw + ib) * pw;
        pw *= A0;
    }
    P_all[b * DM + c] = acc;
    for (int l = 1; l < NLAYER; ++l) P_all[l * BATCH * DM + b * DM + c] = 0.f;
    for (int e = 0; e < 4; ++e) pooled[e * BATCH * DM + b * DM + c] = 0.f;
    if (b == 0) {
        for (int l = 0; l < NLAYER; ++l) {
            float Al = 1.f / (1.f + expf(-Ap[l * DM + c]));
            logA_all[l * DM + c] = logf(Al);
            CB_all[l * DM + c]   = Bp[l * DM + c] * Cp[l * DM + c];
        }
    }
}

// ---------------- fused MFMA layer kernel ----------------
__global__ __launch_bounds__(512, 2) void k_gemm(
    const float* h, float* hout,
    const float* __restrict__ pW, const float* __restrict__ pb,
    const float* __restrict__ lng, const float* __restrict__ lnb,
    const float* __restrict__ Dp,
    const float* __restrict__ P, const float* __restrict__ logA,
    const float* __restrict__ CB,
    const float* __restrict__ logA_next, float* __restrict__ P_next,
    float* __restrict__ pooled, int exitSlot)
{
    __shared__ __align__(16) char smem[51200];
    u16* Ash = (u16*)smem;            // [64][APAD]
    u16* Asl = Ash + 64 * APAD;
    u16* Bsh = Asl + 64 * APAD;       // [256][APAD]
    u16* Bsl = Bsh + 256 * APAD;
    float* Y     = (float*)smem;      // [32][YPAD]  (epilogue, aliases stage bufs)
    float* csumb = Y + 32 * YPAD;     // [8][256]

    int tid  = threadIdx.x;
    int brow = blockIdx.x * 64;
    int b    = brow >> 11;
    int lane = tid & 63;
    int wv   = tid >> 6;              // 0..7
    int wm   = wv >> 2;               // 0..1 (row half)
    int wn   = wv & 3;                // 0..3 (col quarter)
    int fr   = lane & 15;
    int fq   = lane >> 4;

    f32x4 acc[2][4];
#pragma unroll
    for (int m = 0; m < 2; ++m)
#pragma unroll
        for (int n = 0; n < 4; ++n) acc[m][n] = (f32x4){0.f, 0.f, 0.f, 0.f};

    int srow = tid >> 3;              // 0..63
    int k4   = (tid & 7) * 4;         // 0..28
    int gr_s = brow + srow;
    int u_s  = (LSEQ - 1) - (gr_s & (LSEQ - 1));

    for (int kc = 0; kc < DM; kc += KC) {
        // ---- stage A (gelu(D*h + tail), split hi/lo) ----
        {
            int kk = kc + k4;
            float4 hv = *(const float4*)&h[gr_s * DM + kk];
            float4 dv = *(const float4*)&Dp[kk];
            float v0 = hv.x * dv.x, v1 = hv.y * dv.y, v2 = hv.z * dv.z, v3 = hv.w * dv.w;
            if (u_s <= EMAX) {
                float uf = (float)u_s;
                float4 la = *(const float4*)&logA[kk];
                float4 cb = *(const float4*)&CB[kk];
                float4 Pv = *(const float4*)&P[b * DM + kk];
                v0 += cb.x * expf(uf * la.x) * Pv.x;
                v1 += cb.y * expf(uf * la.y) * Pv.y;
                v2 += cb.z * expf(uf * la.z) * Pv.z;
                v3 += cb.w * expf(uf * la.w) * Pv.w;
            }
            u16 h0, l0, h1, l1, h2, l2, h3, l3;
            split2(gelu_exact(v0), h0, l0);
            split2(gelu_exact(v1), h1, l1);
            split2(gelu_exact(v2), h2, l2);
            split2(gelu_exact(v3), h3, l3);
            u16x4 vh = {h0, h1, h2, h3};
            u16x4 vl = {l0, l1, l2, l3};
            *(u16x4*)&Ash[srow * APAD + k4] = vh;
            *(u16x4*)&Asl[srow * APAD + k4] = vl;
        }
        // ---- stage B (pW split hi/lo) ----
#pragma unroll
        for (int it = 0; it < 4; ++it) {
            int n  = (tid >> 3) + it * 64;
            int kk = kc + k4;
            float4 wv4 = *(const float4*)&pW[n * DM + kk];
            u16 h0, l0, h1, l1, h2, l2, h3, l3;
            split2(wv4.x, h0, l0);
            split2(wv4.y, h1, l1);
            split2(wv4.z, h2, l2);
            split2(wv4.w, h3, l3);
            u16x4 vh = {h0, h1, h2, h3};
            u16x4 vl = {l0, l1, l2, l3};
            *(u16x4*)&Bsh[n * APAD + k4] = vh;
            *(u16x4*)&Bsl[n * APAD + k4] = vl;
        }
        __syncthreads();
        // ---- MFMA: one 32-k step ----
        {
            int ko = fq * 8;
            bf16x8 ah[2], al[2], bh[4], bl[4];
#pragma unroll
            for (int m = 0; m < 2; ++m) {
                int ar = (wm * 32 + m * 16 + fr) * APAD + ko;
                ah[m] = *(const bf16x8*)&Ash[ar];
                al[m] = *(const bf16x8*)&Asl[ar];
            }
#pragma unroll
            for (int n = 0; n < 4; ++n) {
                int br = (wn * 64 + n * 16 + fr) * APAD + ko;
                bh[n] = *(const bf16x8*)&Bsh[br];
                bl[n] = *(const bf16x8*)&Bsl[br];
            }
#pragma unroll
            for (int m = 0; m < 2; ++m)
#pragma unroll
                for (int n = 0; n < 4; ++n) {
                    acc[m][n] = __builtin_amdgcn_mfma_f32_16x16x32_bf16(ah[m], bh[n], acc[m][n], 0, 0, 0);
                    acc[m][n] = __builtin_amdgcn_mfma_f32_16x16x32_bf16(ah[m], bl[n], acc[m][n], 0, 0, 0);
                    acc[m][n] = __builtin_amdgcn_mfma_f32_16x16x32_bf16(al[m], bh[n], acc[m][n], 0, 0, 0);
                }
        }
        __syncthreads();
    }

    // ---- epilogue: residual + LN + store + pooled + P_next ----
    int c0 = lane * 4;
    float4 pbv = *(const float4*)&pb[c0];
    float4 lg  = *(const float4*)&lng[c0];
    float4 lb  = *(const float4*)&lnb[c0];
    float cs0 = 0.f, cs1 = 0.f, cs2 = 0.f, cs3 = 0.f;

#pragma unroll
    for (int p = 0; p < 2; ++p) {
        if (wm == p) {
#pragma unroll
            for (int m = 0; m < 2; ++m)
#pragma unroll
                for (int n = 0; n < 4; ++n)
#pragma unroll
                    for (int r = 0; r < 4; ++r)
                        Y[(m * 16 + fq * 4 + r) * YPAD + wn * 64 + n * 16 + fr] = acc[m][n][r];
        }
        __syncthreads();
#pragma unroll
        for (int i = 0; i < 4; ++i) {
            int lr = wv * 4 + i;
            int gr = brow + p * 32 + lr;
            float4 o2 = *(float4*)&Y[lr * YPAD + c0];
            float4 hv = *(const float4*)&h[gr * DM + c0];
            float y0 = hv.x + o2.x + pbv.x;
            float y1 = hv.y + o2.y + pbv.y;
            float y2 = hv.z + o2.z + pbv.z;
            float y3 = hv.w + o2.w + pbv.w;
            float s  = y0 + y1 + y2 + y3;
            float ss = y0 * y0 + y1 * y1 + y2 * y2 + y3 * y3;
#pragma unroll
            for (int off = 1; off < 64; off <<= 1) {
                s  += __shfl_xor(s, off);
                ss += __shfl_xor(ss, off);
            }
            float mean = s * (1.f / 256.f);
            float var  = ss * (1.f / 256.f) - mean * mean;
            float rstd = rsqrtf(var + LN_EPS);
            float o0 = (y0 - mean) * rstd * lg.x + lb.x;
            float o1 = (y1 - mean) * rstd * lg.y + lb.y;
            float o2o = (y2 - mean) * rstd * lg.z + lb.z;
            float o3 = (y3 - mean) * rstd * lg.w + lb.w;
            float4 ov = {o0, o1, o2o, o3};
            *(float4*)&hout[gr * DM + c0] = ov;
            cs0 += o0; cs1 += o1; cs2 += o2o; cs3 += o3;
            int t = gr & (LSEQ - 1);
            if (P_next != nullptr && t <= EMAX) {
                float tf = (float)t;
                float4 la = *(const float4*)&logA_next[c0];
                atomicAdd(&P_next[b * DM + c0 + 0], o0  * expf(tf * la.x));
                atomicAdd(&P_next[b * DM + c0 + 1], o1  * expf(tf * la.y));
                atomicAdd(&P_next[b * DM + c0 + 2], o2o * expf(tf * la.z));
                atomicAdd(&P_next[b * DM + c0 + 3], o3  * expf(tf * la.w));
            }
        }
        __syncthreads();
    }

    if (exitSlot >= 0) {
        csumb[wv * DM + c0 + 0] = cs0;
        csumb[wv * DM + c0 + 1] = cs1;
        csumb[wv * DM + c0 + 2] = cs2;
        csumb[wv * DM + c0 + 3] = cs3;
        __syncthreads();
        if (tid < 64) {
            int cc = tid * 4;
#pragma unroll
            for (int q = 0; q < 4; ++q) {
                float sm = 0.f;
#pragma unroll
                for (int w = 0; w < 8; ++w) sm += csumb[w * DM + cc + q];
                atomicAdd(&pooled[exitSlot * (BATCH * DM) + b * DM + cc + q], sm);
            }
        }
    }
}

// ---------------- head ----------------
__global__ void k_head(const float* __restrict__ pooled, const float* __restrict__ hW,
                       const float* __restrict__ hb, float* __restrict__ out) {
    int tid = threadIdx.x;
    if (tid >= 96) return;
    int e = tid / 24;
    int r = tid % 24;
    int b = r / 3;
    int n = r % 3;
    const float* pv = &pooled[e * (BATCH * DM) + b * DM];
    const float* wv = &hW[(e * 3 + n) * DM];
    float acc = 0.f;
    for (int c = 0; c < DM; ++c) acc += pv[c] * wv[c];
    out[e * 24 + b * 3 + n] = acc * (1.f / (float)LSEQ) + hb[e * 3 + n];
}

extern "C" void kernel_launch(void* const* d_in, const int* in_sizes, int n_in,
                              void* d_out, int out_size, void* d_ws, size_t ws_size,
                              hipStream_t stream) {
    const float* x   = (const float*)d_in[0];
    const float* inW = (const float*)d_in[1];
    const float* inb = (const float*)d_in[2];
    const float* Ap  = (const float*)d_in[3];
    const float* Bp  = (const float*)d_in[4];
    const float* Cp  = (const float*)d_in[5];
    const float* Dp  = (const float*)d_in[6];
    const float* pW  = (const float*)d_in[7];
    const float* pb  = (const float*)d_in[8];
    const float* lng = (const float*)d_in[9];
    const float* lnb = (const float*)d_in[10];
    const float* hW  = (const float*)d_in[11];
    const float* hb  = (const float*)d_in[12];
    float* out = (float*)d_out;

    float* ws = (float*)d_ws;
    float* h        = ws;                            // 4194304
    float* P_all    = h + BATCH * LSEQ * DM;         // 8*8*256 = 16384
    float* logA_all = P_all + NLAYER * BATCH * DM;   // 2048
    float* CB_all   = logA_all + NLAYER * DM;        // 2048
    float* pooled   = CB_all + NLAYER * DM;          // 8192

    k_prep0<<<BATCH, 256, 0, stream>>>(x, inW, inb, Ap, Bp, Cp,
                                       P_all, logA_all, CB_all, pooled);
    k_init<<<4096, 256, 0, stream>>>(x, inW, inb, h);
    for (int l = 0; l < NLAYER; ++l) {
        int ex = (l == 1) ? 0 : (l == 3) ? 1 : (l == 5) ? 2 : (l == 7) ? 3 : -1;
        const float* lan = (l < NLAYER - 1) ? (logA_all + (l + 1) * DM) : nullptr;
        float* pn        = (l < NLAYER - 1) ? (P_all + (l + 1) * BATCH * DM) : nullptr;
        k_gemm<<<(BATCH * LSEQ) / 64, 512, 0, stream>>>(
            h, h, pW + l * DM * DM, pb + l * DM, lng + l * DM, lnb + l * DM,
            Dp + l * DM, P_all + l * BATCH * DM, logA_all + l * DM, CB_all + l * DM,
            lan, pn, pooled, ex);
    }
    k_head<<<1, 128, 0, stream>>>(pooled, hW, hb, out);
}